// Round 4
// baseline (106.319 us; speedup 1.0000x reference)
//
#include <hip/hip_runtime.h>

// NonLocalMean: x (4,64,128,128) fp32, K=7 (rad 3), HEADS=4 -> mid=16.
// w_p = exp(2<n_p,c> - ||n_p||^2 - ||c||^2) = exp(-||n_p-c||^2) <= ~1, so no
// online-softmax rescale is needed. out = x + (sum_p w_p n_p)/(sum_p w_p).
// Zero-padded OOB patches are zero vectors contributing exp(-||c||^2).
//
// R4: 1 output/thread (262144 threads = 4 waves/SIMD resident, 2x R3) to fix
// the latency-bound 35%-of-pipe utilization. Neighbors stored in LDS as bf16
// (RNE): record = 8 packed dwords, stride 10 dwords (40B) -> ds_read_b64
// bank-pairs (5*pix+k)%16 perfectly balanced. Norms (fp32, from QUANTIZED
// values so the exp<=1 property holds) in a separate stride-1 array.
// Center kept exact fp32 from global (residual + dot accuracy). Staging and
// norm computation fused: single barrier. Dot uses 4 interleaved partials.

#define TW    16
#define RAD   3
#define HWD   22                 // 16 + 6
#define NPIX  (HWD * HWD)        // 484
#define MID   16
#define PSTRD 10                 // dwords per pixel record (40 B)
#define IMG   128
#define PLANE (IMG * IMG)

__device__ __forceinline__ unsigned bf16rne(float v) {
    unsigned u = __float_as_uint(v);
    u += 0x7fffu + ((u >> 16) & 1u);
    return u >> 16;               // bf16 bits
}

__global__ __launch_bounds__(256, 4)
void nlm_kernel(const float* __restrict__ x, float* __restrict__ out) {
    const int g   = blockIdx.z & 3;
    const int b   = blockIdx.z >> 2;
    const int tx0 = blockIdx.x * TW;
    const int ty0 = blockIdx.y * TW;

    __shared__ __align__(16) unsigned recd[NPIX * PSTRD];  // 19,360 B
    __shared__ float nn[NPIX];                             //  1,936 B

    const int tid = threadIdx.x;
    const int lx  = tid & 15;
    const int ly  = tid >> 4;
    const float* xb = x + (size_t)(b * 64 + g * MID) * PLANE;

    // ---- exact fp32 center (issued before the barrier; L2-hot) ----
    const float* cp = xb + (ty0 + ly) * IMG + (tx0 + lx);
    float ctr[MID];
    #pragma unroll
    for (int c = 0; c < MID; ++c) ctr[c] = cp[c * PLANE];
    float ccA = 0.f, ccB = 0.f;
    #pragma unroll
    for (int c = 0; c < MID; c += 2) {
        ccA = fmaf(ctr[c], ctr[c], ccA);
        ccB = fmaf(ctr[c + 1], ctr[c + 1], ccB);
    }
    const float cc = ccA + ccB;

    // ---- stage halo as bf16 + fp32 norms (single pass, one barrier) ----
    for (int i = tid; i < NPIX; i += 256) {
        const int yy = i / HWD;
        const int xx = i - yy * HWD;
        const int gy = ty0 + yy - RAD;
        const int gx = tx0 + xx - RAD;
        const bool in = ((unsigned)gy < (unsigned)IMG) & ((unsigned)gx < (unsigned)IMG);
        const float* p = xb + gy * IMG + gx;
        unsigned pk[8];
        float ss = 0.f;
        #pragma unroll
        for (int k = 0; k < 8; ++k) {
            const float v0 = in ? p[(2 * k) * PLANE] : 0.f;
            const float v1 = in ? p[(2 * k + 1) * PLANE] : 0.f;
            const unsigned q0 = bf16rne(v0);
            const unsigned q1 = bf16rne(v1);
            pk[k] = q0 | (q1 << 16);
            const float r0 = __uint_as_float(q0 << 16);
            const float r1 = __uint_as_float(q1 << 16);
            ss = fmaf(r0, r0, ss);
            ss = fmaf(r1, r1, ss);
        }
        unsigned* rp = &recd[i * PSTRD];
        #pragma unroll
        for (int k = 0; k < 4; ++k)
            *reinterpret_cast<uint2*>(rp + 2 * k) = make_uint2(pk[2 * k], pk[2 * k + 1]);
        nn[i] = ss;
    }
    __syncthreads();

    // ---- main: 49 visits, 1 output per thread ----
    float acc[MID];
    #pragma unroll
    for (int c = 0; c < MID; ++c) acc[c] = 0.f;
    float sA = 0.f, sB = 0.f;

    for (int wy = 0; wy < 7; ++wy) {
        const unsigned* rowp = &recd[((ly + wy) * HWD + lx) * PSTRD];
        const float*    nrow = &nn[(ly + wy) * HWD + lx];
        #pragma unroll
        for (int wx = 0; wx < 7; ++wx) {
            const unsigned* rp = rowp + wx * PSTRD;   // compile-time offset
            const uint2 p0 = *reinterpret_cast<const uint2*>(rp + 0);
            const uint2 p1 = *reinterpret_cast<const uint2*>(rp + 2);
            const uint2 p2 = *reinterpret_cast<const uint2*>(rp + 4);
            const uint2 p3 = *reinterpret_cast<const uint2*>(rp + 6);
            float nb[MID];
            {
                const unsigned w0 = p0.x, w1 = p0.y, w2 = p1.x, w3 = p1.y;
                const unsigned w4 = p2.x, w5 = p2.y, w6 = p3.x, w7 = p3.y;
                nb[0]  = __uint_as_float(w0 << 16); nb[1]  = __uint_as_float(w0 & 0xffff0000u);
                nb[2]  = __uint_as_float(w1 << 16); nb[3]  = __uint_as_float(w1 & 0xffff0000u);
                nb[4]  = __uint_as_float(w2 << 16); nb[5]  = __uint_as_float(w2 & 0xffff0000u);
                nb[6]  = __uint_as_float(w3 << 16); nb[7]  = __uint_as_float(w3 & 0xffff0000u);
                nb[8]  = __uint_as_float(w4 << 16); nb[9]  = __uint_as_float(w4 & 0xffff0000u);
                nb[10] = __uint_as_float(w5 << 16); nb[11] = __uint_as_float(w5 & 0xffff0000u);
                nb[12] = __uint_as_float(w6 << 16); nb[13] = __uint_as_float(w6 & 0xffff0000u);
                nb[14] = __uint_as_float(w7 << 16); nb[15] = __uint_as_float(w7 & 0xffff0000u);
            }
            // dot as 4 interleaved partials (short dep chains)
            float d0 = 0.f, d1 = 0.f, d2 = 0.f, d3 = 0.f;
            #pragma unroll
            for (int c = 0; c < MID; c += 4) {
                d0 = fmaf(nb[c + 0], ctr[c + 0], d0);
                d1 = fmaf(nb[c + 1], ctr[c + 1], d1);
                d2 = fmaf(nb[c + 2], ctr[c + 2], d2);
                d3 = fmaf(nb[c + 3], ctr[c + 3], d3);
            }
            const float dot = (d0 + d1) + (d2 + d3);
            const float a = fmaf(2.f, dot, -(nrow[wx] + cc));
            const float w = __expf(a);
            if (wx & 1) sB += w; else sA += w;
            #pragma unroll
            for (int c = 0; c < MID; ++c) acc[c] = fmaf(w, nb[c], acc[c]);
        }
    }

    const float inv = 1.f / (sA + sB);
    float* ob = out + (size_t)(b * 64 + g * MID) * PLANE
                    + (size_t)(ty0 + ly) * IMG + (tx0 + lx);
    #pragma unroll
    for (int c = 0; c < MID; ++c)
        ob[c * PLANE] = fmaf(acc[c], inv, ctr[c]);
}

extern "C" void kernel_launch(void* const* d_in, const int* in_sizes, int n_in,
                              void* d_out, int out_size, void* d_ws, size_t ws_size,
                              hipStream_t stream) {
    const float* x = (const float*)d_in[0];
    float* out = (float*)d_out;
    dim3 grid(IMG / TW, IMG / TW, 16);   // 8 x 8 x (B=4 * HEADS=4) = 1024 blocks
    nlm_kernel<<<grid, 256, 0, stream>>>(x, out);
}

// Round 5
// 33.882 us; speedup vs baseline: 3.1379x; 3.1379x over previous
//
#include <hip/hip_runtime.h>

// NonLocalMean: x (4,64,128,128) fp32, K=7 (rad 3), HEADS=4 -> mid=16.
// w_p = exp(2<n_p,c> - ||n_p||^2 - ||c||^2) = exp(-||n_p-c||^2) <= ~1 (the
// softmax max is 0 at the center pixel) -> plain sum, no online rescale.
// out = x + (sum_p w_p n_p)/(sum_p w_p). Zero-padded OOB patches are zero
// vectors contributing exp(-||c||^2) to the denominator.
//
// R5 = R4 structure with the spill fixed. R4's 106us came from scratch
// traffic (WRITE 310MB vs 16MB payload): full wy*wx unroll + the hard
// 128-VGPR cap from __launch_bounds__(256,4) forced spills. Fix: wy loop
// kept rolled (#pragma unroll 1) and no min-occupancy clamp (cap 512).
// Everything else unchanged: 1 output/thread (16 waves/CU via <=128 VGPR +
// 21.5KB LDS), bf16 LDS records (8 packed dwords, stride 10 -> ds_read_b64
// bank-pairs (5p+k)%16 balanced, compile-time offsets), fp32 norms from the
// QUANTIZED values (keeps exp<=1 exact), exact-fp32 center from global for
// residual+dot accuracy, staging+norms fused behind a single barrier.

#define TW    16
#define RAD   3
#define HWD   22                 // 16 + 6
#define NPIX  (HWD * HWD)        // 484
#define MID   16
#define PSTRD 10                 // dwords per pixel record (40 B)
#define IMG   128
#define PLANE (IMG * IMG)

__device__ __forceinline__ unsigned bf16rne(float v) {
    unsigned u = __float_as_uint(v);
    u += 0x7fffu + ((u >> 16) & 1u);
    return u >> 16;               // bf16 bits
}

__global__ __launch_bounds__(256)
void nlm_kernel(const float* __restrict__ x, float* __restrict__ out) {
    const int g   = blockIdx.z & 3;
    const int b   = blockIdx.z >> 2;
    const int tx0 = blockIdx.x * TW;
    const int ty0 = blockIdx.y * TW;

    __shared__ __align__(16) unsigned recd[NPIX * PSTRD];  // 19,360 B
    __shared__ float nn[NPIX];                             //  1,936 B

    const int tid = threadIdx.x;
    const int lx  = tid & 15;
    const int ly  = tid >> 4;
    const float* xb = x + (size_t)(b * 64 + g * MID) * PLANE;

    // ---- exact fp32 center (issued early; L2-hot; needed for residual) ----
    const float* cp = xb + (ty0 + ly) * IMG + (tx0 + lx);
    float ctr[MID];
    #pragma unroll
    for (int c = 0; c < MID; ++c) ctr[c] = cp[c * PLANE];
    float ccA = 0.f, ccB = 0.f;
    #pragma unroll
    for (int c = 0; c < MID; c += 2) {
        ccA = fmaf(ctr[c], ctr[c], ccA);
        ccB = fmaf(ctr[c + 1], ctr[c + 1], ccB);
    }
    const float cc = ccA + ccB;

    // ---- stage halo as bf16 + fp32 norms (single pass, one barrier) ----
    #pragma unroll 1
    for (int i = tid; i < NPIX; i += 256) {
        const int yy = i / HWD;
        const int xx = i - yy * HWD;
        const int gy = ty0 + yy - RAD;
        const int gx = tx0 + xx - RAD;
        const bool in = ((unsigned)gy < (unsigned)IMG) & ((unsigned)gx < (unsigned)IMG);
        const float* p = xb + gy * IMG + gx;
        unsigned pk[8];
        float ss = 0.f;
        #pragma unroll
        for (int k = 0; k < 8; ++k) {
            const float v0 = in ? p[(2 * k) * PLANE] : 0.f;
            const float v1 = in ? p[(2 * k + 1) * PLANE] : 0.f;
            const unsigned q0 = bf16rne(v0);
            const unsigned q1 = bf16rne(v1);
            pk[k] = q0 | (q1 << 16);
            const float r0 = __uint_as_float(q0 << 16);
            const float r1 = __uint_as_float(q1 << 16);
            ss = fmaf(r0, r0, ss);
            ss = fmaf(r1, r1, ss);
        }
        unsigned* rp = &recd[i * PSTRD];
        #pragma unroll
        for (int k = 0; k < 4; ++k)
            *reinterpret_cast<uint2*>(rp + 2 * k) = make_uint2(pk[2 * k], pk[2 * k + 1]);
        nn[i] = ss;
    }
    __syncthreads();

    // ---- main: 49 visits, 1 output per thread; wy ROLLED (spill control) ----
    float acc[MID];
    #pragma unroll
    for (int c = 0; c < MID; ++c) acc[c] = 0.f;
    float s = 0.f;

    #pragma unroll 1
    for (int wy = 0; wy < 7; ++wy) {
        const unsigned* rowp = &recd[((ly + wy) * HWD + lx) * PSTRD];
        const float*    nrow = &nn[(ly + wy) * HWD + lx];
        #pragma unroll
        for (int wx = 0; wx < 7; ++wx) {
            const unsigned* rp = rowp + wx * PSTRD;   // compile-time offset
            const uint2 p0 = *reinterpret_cast<const uint2*>(rp + 0);
            const uint2 p1 = *reinterpret_cast<const uint2*>(rp + 2);
            const uint2 p2 = *reinterpret_cast<const uint2*>(rp + 4);
            const uint2 p3 = *reinterpret_cast<const uint2*>(rp + 6);
            float nb[MID];
            nb[0]  = __uint_as_float(p0.x << 16); nb[1]  = __uint_as_float(p0.x & 0xffff0000u);
            nb[2]  = __uint_as_float(p0.y << 16); nb[3]  = __uint_as_float(p0.y & 0xffff0000u);
            nb[4]  = __uint_as_float(p1.x << 16); nb[5]  = __uint_as_float(p1.x & 0xffff0000u);
            nb[6]  = __uint_as_float(p1.y << 16); nb[7]  = __uint_as_float(p1.y & 0xffff0000u);
            nb[8]  = __uint_as_float(p2.x << 16); nb[9]  = __uint_as_float(p2.x & 0xffff0000u);
            nb[10] = __uint_as_float(p2.y << 16); nb[11] = __uint_as_float(p2.y & 0xffff0000u);
            nb[12] = __uint_as_float(p3.x << 16); nb[13] = __uint_as_float(p3.x & 0xffff0000u);
            nb[14] = __uint_as_float(p3.y << 16); nb[15] = __uint_as_float(p3.y & 0xffff0000u);

            float d0 = 0.f, d1 = 0.f, d2 = 0.f, d3 = 0.f;
            #pragma unroll
            for (int c = 0; c < MID; c += 4) {
                d0 = fmaf(nb[c + 0], ctr[c + 0], d0);
                d1 = fmaf(nb[c + 1], ctr[c + 1], d1);
                d2 = fmaf(nb[c + 2], ctr[c + 2], d2);
                d3 = fmaf(nb[c + 3], ctr[c + 3], d3);
            }
            const float dot = (d0 + d1) + (d2 + d3);
            const float a = fmaf(2.f, dot, -(nrow[wx] + cc));
            const float w = __expf(a);
            s += w;
            #pragma unroll
            for (int c = 0; c < MID; ++c) acc[c] = fmaf(w, nb[c], acc[c]);
        }
    }

    const float inv = 1.f / s;
    float* ob = out + (size_t)(b * 64 + g * MID) * PLANE
                    + (size_t)(ty0 + ly) * IMG + (tx0 + lx);
    #pragma unroll
    for (int c = 0; c < MID; ++c)
        ob[c * PLANE] = fmaf(acc[c], inv, ctr[c]);
}

extern "C" void kernel_launch(void* const* d_in, const int* in_sizes, int n_in,
                              void* d_out, int out_size, void* d_ws, size_t ws_size,
                              hipStream_t stream) {
    const float* x = (const float*)d_in[0];
    float* out = (float*)d_out;
    dim3 grid(IMG / TW, IMG / TW, 16);   // 8 x 8 x (B=4 * HEADS=4) = 1024 blocks
    nlm_kernel<<<grid, 256, 0, stream>>>(x, out);
}